// Round 5
// baseline (607.641 us; speedup 1.0000x reference)
//
#include <hip/hip_runtime.h>
#include <hip/hip_bf16.h>
#include <stdint.h>

#define G_ 8
#define T_ 1024
#define K_ 7168
#define N_ 2048
#define KB_ (K_/128)   // 56
#define NB_ (N_/128)   // 16
#define NT8_ 56        // K-tiles of 128

typedef __attribute__((ext_vector_type(4))) float f32x4;
typedef __attribute__((ext_vector_type(8))) int   i32x8;

typedef __attribute__((address_space(3))) uint32_t lds_u32_t;
typedef const __attribute__((address_space(1))) uint32_t gbl_u32_t;

__device__ __forceinline__ void gload_lds16(const void* gsrc, const void* ldst)
{
    __builtin_amdgcn_global_load_lds(
        (gbl_u32_t*)(uintptr_t)gsrc,
        (lds_u32_t*)(uint32_t)(uintptr_t)ldst, 16, 0, 0);
}

__device__ __forceinline__ void blockbar()
{
    asm volatile("" ::: "memory");
    __builtin_amdgcn_s_barrier();
    asm volatile("" ::: "memory");
}

// ---------------------------------------------------------------------------
// Kernel 1: activation quant -> fp8 code bytes + scale table.
//   One reciprocal per 128-block (448/amax), multiplies instead of divides.
//   scale layout: [g][tb=t>>8][kb][t&255].
// ---------------------------------------------------------------------------
__global__ __launch_bounds__(256) void act_quant_kernel(
    const float* __restrict__ xs, uint8_t* __restrict__ xq8,
    float* __restrict__ ascale)
{
    const int grp = (blockIdx.x * 256 + threadIdx.x) >> 5;   // quant-block id
    const int l   = threadIdx.x & 31;
    const size_t base = (size_t)grp * 128 + (size_t)l * 4;

    const float4 v = *(const float4*)(xs + base);
    float am = fmaxf(fmaxf(fabsf(v.x), fabsf(v.y)), fmaxf(fabsf(v.z), fabsf(v.w)));
#pragma unroll
    for (int off = 1; off <= 16; off <<= 1)
        am = fmaxf(am, __shfl_xor(am, off, 64));

    const float rs = 448.0f / am;              // one precise div per block
    const float s  = am * (1.0f / 448.0f);     // stored scale (<=1ulp vs am/448)

    int pk = __builtin_amdgcn_cvt_pk_fp8_f32(v.x * rs, v.y * rs, 0, false);
    pk     = __builtin_amdgcn_cvt_pk_fp8_f32(v.z * rs, v.w * rs, pk, true);
    *(uint32_t*)(xq8 + base) = (uint32_t)pk;

    if (l == 0) {
        const int kb = grp % KB_;
        const int t  = (grp / KB_) & (T_ - 1);
        const int g  = grp / (KB_ * T_);
        ascale[(((size_t)(g * 4 + (t >> 8))) * KB_ + kb) * 256 + (t & 255)] = s;
    }
}

// ---------------------------------------------------------------------------
// Kernel 2: blockwise-fp8 grouped GEMM with FUSED weight recode.
//   A (fp8 from act_quant): global_load_lds, pre-swizzled source.
//   B (fp32 codes): reg-staged dwordx4 loads -> cvt_pk_fp8 -> swizzled
//   ds_write_b128; loads issued 2 phases before use, vmcnt(2) counted drain.
//   mfma_scale_f32_16x16x128_f8f6f4 (unit E8M0 scales) + fp32 block rescale.
//   LDS: A 2x32K | B 2x32K | a-scales 2x8K = 144 KB, 1 WG/CU, 8 waves.
// ---------------------------------------------------------------------------
union Frag { i32x8 v; struct { int4 lo, hi; } p; };

#define RD_A(mh)                                                              \
  { _Pragma("unroll") for (int m = 0; m < 4; ++m) {                           \
      const int r  = wrow + ((mh)*4 + m)*16 + l15;                            \
      const int rx = (r & 7) << 4;                                            \
      const char* bp = smem + cb*32768 + r*128;                               \
      aF[m].p.lo = *(const int4*)(bp + ((lhi*32) ^ rx));                      \
      aF[m].p.hi = *(const int4*)(bp + ((lhi*32 + 16) ^ rx));                 \
      const float4 sv = *(const float4*)(smem + 131072 + ((u>>3)&1)*8192 +    \
          (u & 7)*1024 + (wrow + ((mh)*4 + m)*16 + lhi*4)*4);                 \
      asw[m][0] = sv.x*wsc; asw[m][1] = sv.y*wsc;                             \
      asw[m][2] = sv.z*wsc; asw[m][3] = sv.w*wsc;                             \
  } }

#define RD_B(nh)                                                              \
  { _Pragma("unroll") for (int n = 0; n < 2; ++n) {                           \
      const int r  = wcol + ((nh)*2 + n)*16 + l15;                            \
      const int rx = (r & 7) << 4;                                            \
      const char* bp = smem + 65536 + cb*32768 + r*128;                       \
      bF[(nh)*2+n].p.lo = *(const int4*)(bp + ((lhi*32) ^ rx));               \
      bF[(nh)*2+n].p.hi = *(const int4*)(bp + ((lhi*32 + 16) ^ rx));          \
  } }

#define MM(mh, nh)                                                            \
  { _Pragma("unroll") for (int m = 0; m < 4; ++m) {                           \
      _Pragma("unroll") for (int n = 0; n < 2; ++n) {                         \
        f32x4 blk = __builtin_amdgcn_mfma_scale_f32_16x16x128_f8f6f4(         \
            aF[m].v, bF[(nh)*2+n].v, z4, 0, 0,                                \
            0, 0x7F7F7F7F, 0, 0x7F7F7F7F);                                    \
        _Pragma("unroll") for (int j = 0; j < 4; ++j)                         \
          acc[(mh)*4+m][(nh)*2+n][j] += blk[j] * asw[m][j];                   \
  } } }

#define STG_A8(c, t, b) gload_lds16(pA8[c] + (size_t)(t)*128,                 \
      smem + (b)*32768 + (c)*8192 + tid*16)
#define STG_S(c) gload_lds16(pS + (size_t)(c)*2048,                           \
      smem + 131072 + ((c)&1)*8192 + tid*16)

// issue 8 dwordx4 fp32-code loads for B rows c = h*2, h*2+1 of k-tile t
#define LOAD_B8(t, h)                                                         \
  { _Pragma("unroll") for (int j = 0; j < 2; ++j) {                           \
      const float* s_ = pWf[(h)*2+j] + (size_t)(t)*128;                       \
      _Pragma("unroll") for (int q = 0; q < 4; ++q)                           \
        br[j*4+q] = *(const f32x4*)(s_ + q*4);                                \
  } }

// convert staged regs -> fp8, swizzled ds_write into buf b
#define CVT_WRITE_B(h, b)                                                     \
  { _Pragma("unroll") for (int j = 0; j < 2; ++j) {                           \
      const int row_ = ((h)*2+j)*64 + brow;                                   \
      uint32_t o_[4];                                                         \
      _Pragma("unroll") for (int q = 0; q < 4; ++q) {                         \
        int pk_ = __builtin_amdgcn_cvt_pk_fp8_f32(                            \
            br[j*4+q][0], br[j*4+q][1], 0, false);                            \
        pk_ = __builtin_amdgcn_cvt_pk_fp8_f32(                                \
            br[j*4+q][2], br[j*4+q][3], pk_, true);                           \
        o_[q] = (uint32_t)pk_;                                                \
      }                                                                       \
      *(uint4*)(smem + 65536 + (b)*32768 + row_*128 + bwslot) =               \
          make_uint4(o_[0], o_[1], o_[2], o_[3]);                             \
  } }

__global__ __launch_bounds__(512) void gemm_fp8_kernel(
    const uint8_t* __restrict__ xq8, const float* __restrict__ w,
    const float* __restrict__ ascale, const float* __restrict__ wscale,
    const float* __restrict__ bias, float* __restrict__ y)
{
    __shared__ char smem[147456];

    const int bx0 = blockIdx.x;
    const int bx  = (bx0 & 7) * 32 + (bx0 >> 3);   // XCD swizzle (group->XCD)
    const int g   = bx >> 5;
    const int tm  = (bx >> 3) & 3;
    const int tn  = bx & 7;
    const int t0  = tm * 256, n0 = tn * 256;

    const int tid = threadIdx.x, lane = tid & 63, wid = tid >> 6;
    const int l15 = lane & 15, lhi = lane >> 4;
    const int wrow = (wid >> 2) * 128;
    const int wcol = (wid & 3) * 64;

    const uint8_t* Ag = xq8 + (size_t)g * T_ * K_;
    const float*   Wg = w   + (size_t)g * N_ * K_;

    // A staging: LDS (row = c*64 + tid/8, slot16 = tid%8) <- global slot^row&7
    const int srow = tid >> 3;
    const int xoff = ((tid & 7) ^ (srow & 7)) * 16;
    const uint8_t* pA8[4];
#pragma unroll
    for (int c = 0; c < 4; ++c)
        pA8[c] = Ag + (size_t)(t0 + c * 64 + srow) * K_ + xoff;

    // B reg-staging: thread owns rows {c*64 + tid/8}, 16 fp32 at col (tid&7)*16
    const int brow   = tid >> 3;
    const int bwslot = ((tid & 7) ^ (brow & 7)) * 16;
    const float* pWf[4];
#pragma unroll
    for (int c = 0; c < 4; ++c)
        pWf[c] = Wg + (size_t)(n0 + c * 64 + brow) * K_ + (tid & 7) * 16;

    const float* pS = ascale + ((size_t)(g * 4 + tm) * KB_) * 256 + tid * 4;
    const int wscb = (g * NB_ + ((n0 + wcol) >> 7)) * KB_;

    const f32x4 z4 = {0.f, 0.f, 0.f, 0.f};
    f32x4 acc[8][4] = {};
    Frag aF[4], bF[4];
    float asw[4][4];
    f32x4 br[8];

    // ---- prologue: B tiles 0,1 via reg-cvt; A tiles 0,1; scale chunk 0 ----
    LOAD_B8(0, 0);
    asm volatile("s_waitcnt vmcnt(0)" ::: "memory");
    CVT_WRITE_B(0, 0);
    LOAD_B8(0, 1);
    asm volatile("s_waitcnt vmcnt(0)" ::: "memory");
    CVT_WRITE_B(1, 0);
    LOAD_B8(1, 0);
    asm volatile("s_waitcnt vmcnt(0)" ::: "memory");
    CVT_WRITE_B(0, 1);
    LOAD_B8(1, 1);
    asm volatile("s_waitcnt vmcnt(0)" ::: "memory");
    CVT_WRITE_B(1, 1);
    STG_S(0);
#pragma unroll
    for (int c = 0; c < 4; ++c) STG_A8(c, 0, 0);
#pragma unroll
    for (int c = 0; c < 4; ++c) STG_A8(c, 1, 1);
    // queue: S(1) + A4(t0) + A4(t1) = 9 -> drain S + A(t0), keep A(t1)
    asm volatile("s_waitcnt vmcnt(4)" ::: "memory");
    asm volatile("s_waitcnt lgkmcnt(0)" ::: "memory");
    blockbar();

    for (int u = 0; u < NT8_; ++u) {
        const int cb = u & 1;
        const bool pf = (u + 2 < NT8_);
        const float wsc = wscale[wscb + u];

        // ---- ph1: [scale chunk]; issue B half0(u+2); read A0(+sc), B0 ----
        if ((u & 7) == 0 && u + 8 < NT8_) STG_S((u >> 3) + 1);
        if (pf) LOAD_B8(u + 2, 0);
        RD_A(0); RD_B(0);
        blockbar();
        asm volatile("s_waitcnt lgkmcnt(0)" ::: "memory");
        __builtin_amdgcn_s_setprio(1);
        MM(0, 0);
        __builtin_amdgcn_s_setprio(0);
        blockbar();

        // ---- ph2: stage A c0,c2 (u+2); read B1 ----
        if (pf) { STG_A8(0, u + 2, cb); STG_A8(2, u + 2, cb); }
        RD_B(1);
        blockbar();
        asm volatile("s_waitcnt lgkmcnt(0)" ::: "memory");
        __builtin_amdgcn_s_setprio(1);
        MM(0, 1);
        __builtin_amdgcn_s_setprio(0);
        blockbar();

        // ---- ph3: read A1(+sc); drain B half0 -> cvt+write; issue half1 ----
        RD_A(1);
        if (pf) {
            asm volatile("s_waitcnt vmcnt(2)" ::: "memory");
            CVT_WRITE_B(0, cb);
            LOAD_B8(u + 2, 1);
        }
        blockbar();
        asm volatile("s_waitcnt lgkmcnt(0)" ::: "memory");
        __builtin_amdgcn_s_setprio(1);
        MM(1, 0);
        __builtin_amdgcn_s_setprio(0);
        blockbar();

        // ---- ph4: stage A c1,c3 (u+2); MFMA; drain B half1 -> cvt+write ----
        if (pf) { STG_A8(1, u + 2, cb); STG_A8(3, u + 2, cb); }
        __builtin_amdgcn_s_setprio(1);
        MM(1, 1);
        __builtin_amdgcn_s_setprio(0);
        if (pf) {
            asm volatile("s_waitcnt vmcnt(2)" ::: "memory");
            CVT_WRITE_B(1, cb);
        } else if (u + 1 < NT8_) {
            asm volatile("s_waitcnt vmcnt(0)" ::: "memory");
        }
        asm volatile("s_waitcnt lgkmcnt(0)" ::: "memory");
        blockbar();
    }

    // ---- epilogue: C/D layout col = lane&15, row = (lane>>4)*4 + j ----
    float* Yg = y + (size_t)g * T_ * N_;
#pragma unroll
    for (int n = 0; n < 4; ++n) {
        const int col = n0 + wcol + n * 16 + l15;
        const float bv = bias[g * N_ + col];
#pragma unroll
        for (int m = 0; m < 8; ++m) {
            const int r0 = t0 + wrow + m * 16 + lhi * 4;
#pragma unroll
            for (int j = 0; j < 4; ++j)
                Yg[(size_t)(r0 + j) * N_ + col] = acc[m][n][j] + bv;
        }
    }
}

// ---------------------------------------------------------------------------
extern "C" void kernel_launch(void* const* d_in, const int* in_sizes, int n_in,
                              void* d_out, int out_size, void* d_ws, size_t ws_size,
                              hipStream_t stream)
{
    const float* xs     = (const float*)d_in[0];
    const float* weight = (const float*)d_in[1];
    const float* scale  = (const float*)d_in[2];
    const float* bias   = (const float*)d_in[3];
    float* y = (float*)d_out;

    uint8_t* xq8  = (uint8_t*)d_ws;                      // 58,720,256 B
    float*   ascl = (float*)((char*)d_ws + 58720256);    //  1,835,008 B

    act_quant_kernel<<<(G_ * T_ * KB_) / 8, 256, 0, stream>>>(xs, xq8, ascl);
    gemm_fp8_kernel<<<256, 512, 0, stream>>>(xq8, weight, ascl, scale, bias, y);
}

// Round 6
// 360.732 us; speedup vs baseline: 1.6845x; 1.6845x over previous
//
#include <hip/hip_runtime.h>
#include <hip/hip_bf16.h>
#include <stdint.h>

#define G_ 8
#define T_ 1024
#define K_ 7168
#define N_ 2048
#define KB_ (K_/128)   // 56
#define NB_ (N_/128)   // 16
#define NT8_ 56        // K-tiles of 128

#define ACT_WGS  57344   // (G*T*KB)/8
#define WREC_WGS 28672   // (G*N*K/16)/256

typedef __attribute__((ext_vector_type(4))) float f32x4;
typedef __attribute__((ext_vector_type(8))) int   i32x8;

typedef __attribute__((address_space(3))) uint32_t lds_u32_t;
typedef const __attribute__((address_space(1))) uint32_t gbl_u32_t;

__device__ __forceinline__ void gload_lds16(const void* gsrc, const void* ldst)
{
    __builtin_amdgcn_global_load_lds(
        (gbl_u32_t*)(uintptr_t)gsrc,
        (lds_u32_t*)(uint32_t)(uintptr_t)ldst, 16, 0, 0);
}

__device__ __forceinline__ void blockbar()
{
    asm volatile("" ::: "memory");
    __builtin_amdgcn_s_barrier();
    asm volatile("" ::: "memory");
}

// ---------------------------------------------------------------------------
// Kernel 1: fused prepass.
//   Blocks [0, ACT_WGS): activation quant -> fp8 bytes + scale table
//     (one 448/amax reciprocal per 128-block; scale layout [g][t>>8][kb][t&255])
//   Blocks [ACT_WGS, ACT_WGS+WREC_WGS): weight recode fp32-held-codes -> fp8
// ---------------------------------------------------------------------------
__global__ __launch_bounds__(256) void prep_kernel(
    const float* __restrict__ xs, uint8_t* __restrict__ xq8,
    float* __restrict__ ascale,
    const float* __restrict__ w, uint8_t* __restrict__ wq8)
{
    const int bid = blockIdx.x;
    if (bid < ACT_WGS) {
        const int grp = (bid * 256 + threadIdx.x) >> 5;   // quant-block id
        const int l   = threadIdx.x & 31;
        const size_t base = (size_t)grp * 128 + (size_t)l * 4;

        const float4 v = *(const float4*)(xs + base);
        float am = fmaxf(fmaxf(fabsf(v.x), fabsf(v.y)),
                         fmaxf(fabsf(v.z), fabsf(v.w)));
#pragma unroll
        for (int off = 1; off <= 16; off <<= 1)
            am = fmaxf(am, __shfl_xor(am, off, 64));

        const float rs = 448.0f / am;           // one precise div per block
        const float s  = am * (1.0f / 448.0f);

        int pk = __builtin_amdgcn_cvt_pk_fp8_f32(v.x * rs, v.y * rs, 0, false);
        pk     = __builtin_amdgcn_cvt_pk_fp8_f32(v.z * rs, v.w * rs, pk, true);
        *(uint32_t*)(xq8 + base) = (uint32_t)pk;

        if (l == 0) {
            const int kb = grp % KB_;
            const int t  = (grp / KB_) & (T_ - 1);
            const int g  = grp / (KB_ * T_);
            ascale[(((size_t)(g * 4 + (t >> 8))) * KB_ + kb) * 256 + (t & 255)] = s;
        }
    } else {
        const size_t i = ((size_t)(bid - ACT_WGS) * 256 + threadIdx.x) * 16;
        uint32_t o[4];
#pragma unroll
        for (int q = 0; q < 4; ++q) {
            const float4 a = *(const float4*)(w + i + q * 4);
            int pk = __builtin_amdgcn_cvt_pk_fp8_f32(a.x, a.y, 0, false);
            pk     = __builtin_amdgcn_cvt_pk_fp8_f32(a.z, a.w, pk, true);
            o[q] = (uint32_t)pk;
        }
        *(uint4*)(wq8 + i) = make_uint4(o[0], o[1], o[2], o[3]);
    }
}

// ---------------------------------------------------------------------------
// Kernel 2: blockwise-fp8 grouped GEMM (round-4 structure).
//   256x256 tile, BK=128, 8 waves, 4-phase pipelined, A+B via global_load_lds
//   (pre-swizzled sources), mfma_scale_f32_16x16x128_f8f6f4 with unit E8M0
//   scales, per-128-block fp32 rescale. wscale via prologue LDS table.
//   LDS: A 2x32K | B 2x32K | a-scales 2x8K | wscale 512B.
// ---------------------------------------------------------------------------
union Frag { i32x8 v; struct { int4 lo, hi; } p; };

#define RD_A(mh)                                                              \
  { _Pragma("unroll") for (int m = 0; m < 4; ++m) {                           \
      const int r  = wrow + ((mh)*4 + m)*16 + l15;                            \
      const int rx = (r & 7) << 4;                                            \
      const char* bp = smem + cb*32768 + r*128;                               \
      aF[m].p.lo = *(const int4*)(bp + ((lhi*32) ^ rx));                      \
      aF[m].p.hi = *(const int4*)(bp + ((lhi*32 + 16) ^ rx));                 \
      const float4 sv = *(const float4*)(smem + 131072 + ((u>>3)&1)*8192 +    \
          (u & 7)*1024 + (wrow + ((mh)*4 + m)*16 + lhi*4)*4);                 \
      asw[m][0] = sv.x*wsc; asw[m][1] = sv.y*wsc;                             \
      asw[m][2] = sv.z*wsc; asw[m][3] = sv.w*wsc;                             \
  } }

#define RD_B(nh)                                                              \
  { _Pragma("unroll") for (int n = 0; n < 2; ++n) {                           \
      const int r  = wcol + ((nh)*2 + n)*16 + l15;                            \
      const int rx = (r & 7) << 4;                                            \
      const char* bp = smem + 65536 + cb*32768 + r*128;                       \
      bF[(nh)*2+n].p.lo = *(const int4*)(bp + ((lhi*32) ^ rx));               \
      bF[(nh)*2+n].p.hi = *(const int4*)(bp + ((lhi*32 + 16) ^ rx));          \
  } }

#define MM(mh, nh)                                                            \
  { _Pragma("unroll") for (int m = 0; m < 4; ++m) {                           \
      _Pragma("unroll") for (int n = 0; n < 2; ++n) {                         \
        f32x4 blk = __builtin_amdgcn_mfma_scale_f32_16x16x128_f8f6f4(         \
            aF[m].v, bF[(nh)*2+n].v, z4, 0, 0,                                \
            0, 0x7F7F7F7F, 0, 0x7F7F7F7F);                                    \
        _Pragma("unroll") for (int j = 0; j < 4; ++j)                         \
          acc[(mh)*4+m][(nh)*2+n][j] += blk[j] * asw[m][j];                   \
  } } }

#define STG_A8(c, t, b) gload_lds16(pA8[c] + (size_t)(t)*128,                 \
      smem + (b)*32768 + (c)*8192 + tid*16)
#define STG_B8(c, t, b) gload_lds16(pB8[c] + (size_t)(t)*128,                 \
      smem + 65536 + (b)*32768 + (c)*8192 + tid*16)
#define STG_S(c) gload_lds16(pS + (size_t)(c)*2048,                           \
      smem + 131072 + ((c)&1)*8192 + tid*16)

__global__ __launch_bounds__(512) void gemm_fp8_kernel(
    const uint8_t* __restrict__ xq8, const uint8_t* __restrict__ wq8,
    const float* __restrict__ ascale, const float* __restrict__ wscale,
    const float* __restrict__ bias, float* __restrict__ y)
{
    __shared__ char smem[147968];

    const int bx0 = blockIdx.x;
    const int bx  = (bx0 & 7) * 32 + (bx0 >> 3);   // XCD swizzle: group->XCD
    const int g   = bx >> 5;
    const int tm  = (bx >> 3) & 3;
    const int tn  = bx & 7;
    const int t0  = tm * 256, n0 = tn * 256;

    const int tid = threadIdx.x, lane = tid & 63, wid = tid >> 6;
    const int l15 = lane & 15, lhi = lane >> 4;
    const int wrow = (wid >> 2) * 128;
    const int wcol = (wid & 3) * 64;

    const uint8_t* Ag = xq8 + (size_t)g * T_ * K_;
    const uint8_t* Bg = wq8 + (size_t)g * N_ * K_;

    // staging maps: LDS (row = c*64 + tid/8, slot16 = tid%8) <- global
    // slot16 ^ (row&7); 8KB per call (512 thr x 16B)
    const int srow = tid >> 3;
    const int xoff = ((tid & 7) ^ (srow & 7)) * 16;
    const uint8_t* pA8[4];
    const uint8_t* pB8[4];
#pragma unroll
    for (int c = 0; c < 4; ++c) {
        pA8[c] = Ag + (size_t)(t0 + c * 64 + srow) * K_ + xoff;
        pB8[c] = Bg + (size_t)(n0 + c * 64 + srow) * K_ + xoff;
    }
    const float* pS = ascale + ((size_t)(g * 4 + tm) * KB_) * 256 + tid * 4;

    const f32x4 z4 = {0.f, 0.f, 0.f, 0.f};
    f32x4 acc[8][4] = {};
    Frag aF[4], bF[4];
    float asw[4][4];

    // ---- prologue: wscale table (112 floats, contiguous), scale chunk 0,
    //      tile 0 -> buf0, tile 1 -> buf1 ----
    if (tid < 2 * KB_) {
        const float v = wscale[((size_t)(g * NB_ + tn * 2)) * KB_ + tid];
        *(float*)(smem + 147456 + tid * 4) = v;
    }
    STG_S(0);
#pragma unroll
    for (int c = 0; c < 4; ++c) { STG_A8(c, 0, 0); STG_B8(c, 0, 0); }
#pragma unroll
    for (int c = 0; c < 4; ++c) { STG_A8(c, 1, 1); STG_B8(c, 1, 1); }
    // queue: [ws?, S, 8x tile0, 8x tile1] -> drain ws+S+tile0, keep tile1
    asm volatile("s_waitcnt vmcnt(8)" ::: "memory");
    asm volatile("s_waitcnt lgkmcnt(0)" ::: "memory");
    blockbar();

    const int wsoff = 147456 + ((wcol >> 7) * KB_) * 4;

    for (int u = 0; u < NT8_; ++u) {
        const int cb = u & 1;
        const bool pf = (u + 2 < NT8_);
        const float wsc = *(const float*)(smem + wsoff + u * 4);

        // ---- ph1: [scale chunk]; read A0(+sc), B0 ----
        if ((u & 7) == 0 && u + 8 < NT8_) STG_S((u >> 3) + 1);
        RD_A(0); RD_B(0);
        blockbar();
        asm volatile("s_waitcnt lgkmcnt(0)" ::: "memory");
        __builtin_amdgcn_s_setprio(1);
        MM(0, 0);
        __builtin_amdgcn_s_setprio(0);
        blockbar();

        // ---- ph2: read B1; stage A c0,c2 (rows read in ph1) ----
        RD_B(1);
        if (pf) { STG_A8(0, u + 2, cb); STG_A8(2, u + 2, cb); }
        blockbar();
        asm volatile("s_waitcnt lgkmcnt(0)" ::: "memory");
        __builtin_amdgcn_s_setprio(1);
        MM(0, 1);
        __builtin_amdgcn_s_setprio(0);
        blockbar();

        // ---- ph3: read A1(+sc); stage B c0,c1 (rows read by ph2) ----
        RD_A(1);
        if (pf) { STG_B8(0, u + 2, cb); STG_B8(1, u + 2, cb); }
        blockbar();
        asm volatile("s_waitcnt lgkmcnt(0)" ::: "memory");
        __builtin_amdgcn_s_setprio(1);
        MM(1, 0);
        __builtin_amdgcn_s_setprio(0);
        blockbar();

        // ---- ph4: stage A c1,c3 + B c2,c3; MFMA; counted drain ----
        if (pf) { STG_A8(1, u + 2, cb); STG_A8(3, u + 2, cb);
                  STG_B8(2, u + 2, cb); STG_B8(3, u + 2, cb); }
        __builtin_amdgcn_s_setprio(1);
        MM(1, 1);
        __builtin_amdgcn_s_setprio(0);
        if (pf)                  asm volatile("s_waitcnt vmcnt(8)" ::: "memory");
        else if (u + 1 < NT8_)   asm volatile("s_waitcnt vmcnt(0)" ::: "memory");
        blockbar();
    }

    // ---- epilogue: C/D layout col = lane&15, row = (lane>>4)*4 + j ----
    float* Yg = y + (size_t)g * T_ * N_;
#pragma unroll
    for (int n = 0; n < 4; ++n) {
        const int col = n0 + wcol + n * 16 + l15;
        const float bv = bias[g * N_ + col];
#pragma unroll
        for (int m = 0; m < 8; ++m) {
            const int r0 = t0 + wrow + m * 16 + lhi * 4;
#pragma unroll
            for (int j = 0; j < 4; ++j)
                Yg[(size_t)(r0 + j) * N_ + col] = acc[m][n][j] + bv;
        }
    }
}

// ---------------------------------------------------------------------------
extern "C" void kernel_launch(void* const* d_in, const int* in_sizes, int n_in,
                              void* d_out, int out_size, void* d_ws, size_t ws_size,
                              hipStream_t stream)
{
    const float* xs     = (const float*)d_in[0];
    const float* weight = (const float*)d_in[1];
    const float* scale  = (const float*)d_in[2];
    const float* bias   = (const float*)d_in[3];
    float* y = (float*)d_out;

    uint8_t* xq8  = (uint8_t*)d_ws;                      //  58,720,256 B
    float*   ascl = (float*)((char*)d_ws + 58720256);    //   1,835,008 B
    uint8_t* wq8  = (uint8_t*)((char*)d_ws + 60555264);  // 117,440,512 B

    // 1) fused prepass: act quant + weight recode in one grid
    prep_kernel<<<ACT_WGS + WREC_WGS, 256, 0, stream>>>(
        xs, xq8, ascl, weight, wq8);

    // 2) blockwise-fp8 grouped GEMM
    gemm_fp8_kernel<<<256, 512, 0, stream>>>(xq8, wq8, ascl, scale, bias, y);
}